// Round 7
// baseline (1118.173 us; speedup 1.0000x reference)
//
#include <hip/hip_runtime.h>
#include <hip/hip_bf16.h>
#include <cstdint>
#include <cstddef>

// tanh_max attention, B=4 H=12 S=2048 D=32, fp32 in/out. attn_mask is a
// faithful no-op in the reference -> never read.
//
// R7: MEASUREMENT ROUND. Kernel source identical to R6 (transposed-score,
// LDS-free hot loop). The ONLY change: attn_mfma is launched 4x (idempotent,
// fully overwrites d_out each time). The bench delta vs R6 directly measures
// the attn kernel's in-harness duration:  attn ~= (bench - 926.6)/3.
// R4==R5==R6 to +-0.25us proved theory-only attribution has failed; this
// buys the number that decides whether the residual ~163us is attn at all.

#define SLEN 2048
#define DK   32
#define NBH  48
#define NCH  32   // 32-key chunks per wave (1024 keys)

typedef __attribute__((ext_vector_type(8))) short bf16x8;
typedef __attribute__((ext_vector_type(4))) float f32x4;

__device__ __forceinline__ unsigned pk2(float a, float b) {
    __hip_bfloat162 h = __float22bfloat162_rn(make_float2(a, b));
    union { __hip_bfloat162 h2; unsigned u; } cv; cv.h2 = h; return cv.u;
}

// ---- fused prep ------------------------------------------------------------
// Kbf: A-frag order for tile T=2c+t of chunk c:
//   frag ((bh*128+T)*64 + l) elem j = K[bh][key][(l>>4)*8+j],
//   key = c*32 + 8*((l&15)>>2) + 2*((l&15)&3) + t
// VTf: B-frag order (V^T), natural key order within chunk:
//   frag (((bh*64+c)*2+h)*64 + l) elem j = V[bh][c*32+(l>>4)*8+j][h*16+(l&15)]
__global__ __launch_bounds__(256)
void prep_kv(const float* __restrict__ K, const float* __restrict__ V,
             unsigned short* __restrict__ Kbf, unsigned short* __restrict__ VTf) {
    if (blockIdx.x < NBH * 32) {
        const int b  = blockIdx.x;
        const int bh = b >> 5, kg = b & 31;
        const int tl = threadIdx.x >> 6, l = threadIdx.x & 63;
        const int T  = kg * 4 + tl;
        const int c  = T >> 1, tb = T & 1;
        const int l16 = l & 15;
        const int key = c * 32 + 8 * (l16 >> 2) + 2 * (l16 & 3) + tb;
        const float* src = K + ((size_t)bh * SLEN + key) * DK + (l >> 4) * 8;
        float4 a = *(const float4*)src;
        float4 b4 = *(const float4*)(src + 4);
        union { uint4 q; unsigned u[4]; } o;
        o.u[0] = pk2(a.x, a.y);  o.u[1] = pk2(a.z, a.w);
        o.u[2] = pk2(b4.x, b4.y); o.u[3] = pk2(b4.z, b4.w);
        *(uint4*)(Kbf + (((size_t)bh * 128 + T) * 64 + l) * 8) = o.q;
    } else {
        __shared__ float tile[32][33];
        const int b  = blockIdx.x - NBH * 32;
        const int bh = b >> 6, c = b & 63;
        const int t  = threadIdx.x;
        {
            const int row = t >> 3, c4 = (t & 7) * 4;
            float4 v4 = *(const float4*)(V + ((size_t)bh * SLEN + c * 32 + row) * DK + c4);
            tile[row][c4 + 0] = v4.x; tile[row][c4 + 1] = v4.y;
            tile[row][c4 + 2] = v4.z; tile[row][c4 + 3] = v4.w;
        }
        __syncthreads();
        const int h = t >> 7, l = (t >> 1) & 63, jh = t & 1;
        const int col = h * 16 + (l & 15);
        const int r0  = (l >> 4) * 8 + jh * 4;
        uint2 u;
        u.x = pk2(tile[r0 + 0][col], tile[r0 + 1][col]);
        u.y = pk2(tile[r0 + 2][col], tile[r0 + 3][col]);
        *(uint2*)(VTf + ((((size_t)bh * 64 + c) * 2 + h) * 64 + l) * 8 + jh * 4) = u;
    }
}

// ---- main: MFMA attention, transposed scores, LDS-free hot loop ------------
__global__ __launch_bounds__(256, 4)
void attn_mfma(const float* __restrict__ Q, const unsigned short* __restrict__ Kbf,
               const unsigned short* __restrict__ VTf, float* __restrict__ Out) {
    __shared__ __align__(16) float Red[2][64][20];   // 10240 B

    const int tid  = threadIdx.x;
    const int lane = tid & 63;
    const int wv   = tid >> 6;
    const int quad = lane >> 4;
    const int l16  = lane & 15;
    const int qi   = wv >> 1;
    const int kh   = wv & 1;

    const int b   = blockIdx.x;        // grid = 1536
    const int xcd = b & 7;
    const int i   = b >> 3;
    const int bh  = xcd * 6 + (i % 6);
    const int j   = i / 6;
    const int qbase = (j * 2 + qi) * 32;

    const float sc = 0.17677669529663687f * 1.4426950408889634f;
    union { bf16x8 v; unsigned u[4]; } aQ0, aQ1;
    {
        const float* qp0 = Q + ((size_t)bh * SLEN + qbase + l16) * DK + quad * 8;
        float4 qa = *(const float4*)qp0;
        float4 qb = *(const float4*)(qp0 + 4);
        aQ0.u[0] = pk2(qa.x * sc, qa.y * sc); aQ0.u[1] = pk2(qa.z * sc, qa.w * sc);
        aQ0.u[2] = pk2(qb.x * sc, qb.y * sc); aQ0.u[3] = pk2(qb.z * sc, qb.w * sc);
        const float* qp1 = qp0 + 16 * DK;
        float4 qc = *(const float4*)qp1;
        float4 qd = *(const float4*)(qp1 + 4);
        aQ1.u[0] = pk2(qc.x * sc, qc.y * sc); aQ1.u[1] = pk2(qc.z * sc, qc.w * sc);
        aQ1.u[2] = pk2(qd.x * sc, qd.y * sc); aQ1.u[3] = pk2(qd.z * sc, qd.w * sc);
    }

    const bf16x8* kf = (const bf16x8*)Kbf + ((size_t)bh * 128 + kh * 64) * 64 + lane;
    const bf16x8* vf = (const bf16x8*)VTf + ((size_t)bh * 128 + kh * 64) * 64 + lane;

    f32x4 o00 = {0,0,0,0}, o01 = {0,0,0,0};
    f32x4 o10 = {0,0,0,0}, o11 = {0,0,0,0};
    float den0 = 0.f, den1 = 0.f;
    const f32x4 zero = {0,0,0,0};

    bf16x8 k0 = kf[0], k1 = kf[64];

    for (int c = 0; c < NCH; ++c) {
        f32x4 s00 = __builtin_amdgcn_mfma_f32_16x16x32_bf16(k0, aQ0.v, zero, 0, 0, 0);
        f32x4 s01 = __builtin_amdgcn_mfma_f32_16x16x32_bf16(k1, aQ0.v, zero, 0, 0, 0);
        f32x4 s10 = __builtin_amdgcn_mfma_f32_16x16x32_bf16(k0, aQ1.v, zero, 0, 0, 0);
        f32x4 s11 = __builtin_amdgcn_mfma_f32_16x16x32_bf16(k1, aQ1.v, zero, 0, 0, 0);

        bf16x8 v0 = vf[(size_t)c * 128];
        bf16x8 v1 = vf[(size_t)c * 128 + 64];
        const int cn = (c + 1) & (NCH - 1);
        k0 = kf[(size_t)cn * 128];
        k1 = kf[(size_t)cn * 128 + 64];

        union { bf16x8 v; unsigned u[4]; } aP0, aP1;
        #pragma unroll
        for (int r = 0; r < 4; ++r) {
            float e0  = __builtin_amdgcn_exp2f(s00[r]);
            float en0 = __builtin_amdgcn_exp2f(-s00[r]);
            float e1  = __builtin_amdgcn_exp2f(s01[r]);
            float en1 = __builtin_amdgcn_exp2f(-s01[r]);
            den0 += (e0 + en0) + (e1 + en1);
            aP0.u[r] = pk2(e0 - en0, e1 - en1);
        }
        #pragma unroll
        for (int r = 0; r < 4; ++r) {
            float e0  = __builtin_amdgcn_exp2f(s10[r]);
            float en0 = __builtin_amdgcn_exp2f(-s10[r]);
            float e1  = __builtin_amdgcn_exp2f(s11[r]);
            float en1 = __builtin_amdgcn_exp2f(-s11[r]);
            den1 += (e0 + en0) + (e1 + en1);
            aP1.u[r] = pk2(e0 - en0, e1 - en1);
        }

        o00 = __builtin_amdgcn_mfma_f32_16x16x32_bf16(aP0.v, v0, o00, 0, 0, 0);
        o01 = __builtin_amdgcn_mfma_f32_16x16x32_bf16(aP0.v, v1, o01, 0, 0, 0);
        o10 = __builtin_amdgcn_mfma_f32_16x16x32_bf16(aP1.v, v0, o10, 0, 0, 0);
        o11 = __builtin_amdgcn_mfma_f32_16x16x32_bf16(aP1.v, v1, o11, 0, 0, 0);
    }

    den0 += __shfl_xor(den0, 16); den0 += __shfl_xor(den0, 32);
    den1 += __shfl_xor(den1, 16); den1 += __shfl_xor(den1, 32);

    if (kh == 1) {
        float* r = &Red[qi][lane][0];
        *(f32x4*)(r +  0) = o00; *(f32x4*)(r +  4) = o01;
        *(f32x4*)(r +  8) = o10; *(f32x4*)(r + 12) = o11;
        r[16] = den0; r[17] = den1;
    }
    __syncthreads();
    if (kh == 0) {
        const float* r = &Red[qi][lane][0];
        o00 += *(const f32x4*)(r +  0); o01 += *(const f32x4*)(r +  4);
        o10 += *(const f32x4*)(r +  8); o11 += *(const f32x4*)(r + 12);
        den0 += r[16]; den1 += r[17];

        float* outp = Out + ((size_t)bh * SLEN + qbase) * DK;
        #pragma unroll
        for (int rr = 0; rr < 4; ++rr) {
            float inv0 = 1.0f / __shfl(den0, quad * 4 + rr, 16);
            float inv1 = 1.0f / __shfl(den1, quad * 4 + rr, 16);
            int q0 = quad * 4 + rr;
            int q1 = 16 + quad * 4 + rr;
            outp[(size_t)q0 * DK + l16]      = o00[rr] * inv0;
            outp[(size_t)q0 * DK + 16 + l16] = o01[rr] * inv0;
            outp[(size_t)q1 * DK + l16]      = o10[rr] * inv1;
            outp[(size_t)q1 * DK + 16 + l16] = o11[rr] * inv1;
        }
    }
}

extern "C" void kernel_launch(void* const* d_in, const int* in_sizes, int n_in,
                              void* d_out, int out_size, void* d_ws, size_t ws_size,
                              hipStream_t stream) {
    const float* Q = (const float*)d_in[0];
    const float* K = (const float*)d_in[1];
    const float* V = (const float*)d_in[2];
    // d_in[3] = attn_mask: no-op in reference, never read
    float* Out = (float*)d_out;
    unsigned short* Kbf = (unsigned short*)d_ws;                      // 6.29 MB
    unsigned short* VTf = Kbf + (size_t)NBH * SLEN * DK;              // 6.29 MB

    prep_kv<<<dim3(NBH * 32 + NBH * 64), dim3(256), 0, stream>>>(K, V, Kbf, VTf);
    // MEASUREMENT: 4 idempotent launches; attn ~= (bench - bench_R6)/3.
    attn_mfma<<<dim3(1536), dim3(256), 0, stream>>>(Q, Kbf, VTf, Out);
    attn_mfma<<<dim3(1536), dim3(256), 0, stream>>>(Q, Kbf, VTf, Out);
    attn_mfma<<<dim3(1536), dim3(256), 0, stream>>>(Q, Kbf, VTf, Out);
    attn_mfma<<<dim3(1536), dim3(256), 0, stream>>>(Q, Kbf, VTf, Out);
}

// Round 8
// 956.526 us; speedup vs baseline: 1.1690x; 1.1690x over previous
//
#include <hip/hip_runtime.h>
#include <hip/hip_bf16.h>
#include <cstdint>
#include <cstddef>

// tanh_max attention, B=4 H=12 S=2048 D=32, fp32 in/out. attn_mask is a
// faithful no-op in the reference -> never read.
//
// R8: SINGLE FUSED KERNEL, zero workspace.
//   R7 measured attn ~= 60us -> prep_kv + overhead ~= 95us above the R1
//   1-launch baseline. Can't model prep's cost; eliminate it structurally.
//   - block = 4 waves x 32 queries = 128 q; all waves walk all 2048 keys in
//     32-key chunks, double-buffered in LDS; 1 barrier/chunk.
//   - K staged raw fp32 via global_load_lds (1 instr/wave/chunk) with XOR
//     16B-chunk swizzle: frag ds_read_b128 banks == stride-1 baseline.
//   - V staged via VGPR round trip -> bf16 V^T tile (PROW=36): PV B-frags
//     are 2x ds_read_b64, write side ~2x baseline conflicts (acceptable).
//   - compute spine identical to R6: transposed scores (A=K,B=Q), P packed
//     straight into PV A-frags in registers, per-lane den, no cross-wave
//     combine (each wave owns its 32 queries x all keys).
//   - no d_ws use: graph = 1 node (same structure as R1 baseline 763.5us).

#define SLEN 2048
#define DK   32
#define NBH  48
#define NCH  64    // 32-key chunks
#define PROW 36    // V^T row stride in bf16 (72 B: 8B-aligned b64 frag reads)

typedef __attribute__((ext_vector_type(8))) short bf16x8;
typedef __attribute__((ext_vector_type(4))) float f32x4;
typedef const __attribute__((address_space(1))) void* gas_ptr;
typedef __attribute__((address_space(3))) void*       las_ptr;

__device__ __forceinline__ unsigned pk2(float a, float b) {
    __hip_bfloat162 h = __float22bfloat162_rn(make_float2(a, b));
    union { __hip_bfloat162 h2; unsigned u; } cv; cv.h2 = h; return cv.u;
}
__device__ __forceinline__ unsigned short f2b(float x) {
    __hip_bfloat16 h = __float2bfloat16(x);
    union { __hip_bfloat16 h; unsigned short u; } cv; cv.h = h; return cv.u;
}

__global__ __launch_bounds__(256, 3)
void attn_fused(const float* __restrict__ Q, const float* __restrict__ K,
                const float* __restrict__ V, float* __restrict__ Out) {
    // K stage: [buf][row 0..31][pos 0..7] 16B chunks, chunk c of row r stored
    // at pos c ^ ((r>>1)&7).  V^T stage: [buf][d 0..31][key 0..31] bf16,
    // row stride PROW.
    __shared__ __align__(16) float          Kst[2][32 * 32];     // 8192 B
    __shared__ __align__(16) unsigned short Vst[2][32 * PROW];   // 4608 B

    const int tid  = threadIdx.x;
    const int lane = tid & 63;
    const int wv   = tid >> 6;
    const int quad = lane >> 4;
    const int l16  = lane & 15;

    // XCD-aware head clustering: 6 heads per XCD.
    const int b   = blockIdx.x;        // grid = 768
    const int xcd = b & 7;
    const int i   = b >> 3;            // 0..95
    const int bh  = xcd * 6 + (i % 6);
    const int qblk = i / 6;            // 0..15
    const int qbase = qblk * 128 + wv * 32;

    // Q frags (B-operand), scaled by (1/sqrt(32))*log2(e)
    const float sc = 0.17677669529663687f * 1.4426950408889634f;
    union { bf16x8 v; unsigned u[4]; } aQ0, aQ1;
    {
        const float* qp0 = Q + ((size_t)bh * SLEN + qbase + l16) * DK + quad * 8;
        float4 qa = *(const float4*)qp0;
        float4 qb = *(const float4*)(qp0 + 4);
        aQ0.u[0] = pk2(qa.x * sc, qa.y * sc); aQ0.u[1] = pk2(qa.z * sc, qa.w * sc);
        aQ0.u[2] = pk2(qb.x * sc, qb.y * sc); aQ0.u[3] = pk2(qb.z * sc, qb.w * sc);
        const float* qp1 = qp0 + 16 * DK;
        float4 qc = *(const float4*)qp1;
        float4 qd = *(const float4*)(qp1 + 4);
        aQ1.u[0] = pk2(qc.x * sc, qc.y * sc); aQ1.u[1] = pk2(qc.z * sc, qc.w * sc);
        aQ1.u[2] = pk2(qd.x * sc, qd.y * sc); aQ1.u[3] = pk2(qd.z * sc, qd.w * sc);
    }

    const float* Kh = K + (size_t)bh * SLEN * DK;
    const float* Vh = V + (size_t)bh * SLEN * DK;

    // ---- staging constants (this lane's share of each 32-key chunk) ----
    const int grow   = wv * 8 + (lane >> 3);          // chunk row 0..31
    const int spos   = lane & 7;                      // 16B slot in LDS row
    const int schunk = spos ^ ((grow >> 1) & 7);      // global 16B chunk
    const int ksrc   = grow * 32 + schunk * 4;        // float offset in chunk
    const int vsrc   = grow * 32 + spos * 4;          // V: straight float4
    const int vcol   = spos * 4;                      // V^T dest col base

    // ---- reader constants ----
    const int rkey0 = 8 * (l16 >> 2) + 2 * (l16 & 3); // tile0 (even) key
    const int rxor  = (rkey0 >> 1) & 7;
    const int rc0   = ((2 * quad + 0) ^ rxor) * 4;    // swizzled float offs
    const int rc1   = ((2 * quad + 1) ^ rxor) * 4;

    f32x4 o00 = {0,0,0,0}, o01 = {0,0,0,0};   // q-tile0: O[q][d0..15 / 16..31]
    f32x4 o10 = {0,0,0,0}, o11 = {0,0,0,0};   // q-tile1
    float den0 = 0.f, den1 = 0.f;
    const f32x4 zero = {0,0,0,0};

    // ---- prologue: stage chunk 0 into buf 0 ----
    __builtin_amdgcn_global_load_lds((gas_ptr)(Kh + ksrc),
                                     (las_ptr)(&Kst[0][wv * 256]), 16, 0, 0);
    float4 vreg = *(const float4*)(Vh + vsrc);
    {
        unsigned short* vtw = &Vst[0][0];
        vtw[(vcol + 0) * PROW + grow] = f2b(vreg.x);
        vtw[(vcol + 1) * PROW + grow] = f2b(vreg.y);
        vtw[(vcol + 2) * PROW + grow] = f2b(vreg.z);
        vtw[(vcol + 3) * PROW + grow] = f2b(vreg.w);
    }
    __syncthreads();

    for (int c = 0; c < NCH; ++c) {
        const int buf = c & 1, nbuf = buf ^ 1;
        // issue next-chunk staging loads first (latency overlaps compute)
        if (c + 1 < NCH) {
            __builtin_amdgcn_global_load_lds(
                (gas_ptr)(Kh + (c + 1) * 1024 + ksrc),
                (las_ptr)(&Kst[nbuf][wv * 256]), 16, 0, 0);
            vreg = *(const float4*)(Vh + (c + 1) * 1024 + vsrc);
        }

        // ---- K frags from swizzled LDS (banks == stride-1 baseline) ----
        const float* kb_ = &Kst[buf][0];
        float4 e0 = *(const float4*)(kb_ + rkey0 * 32 + rc0);
        float4 e1 = *(const float4*)(kb_ + rkey0 * 32 + rc1);
        float4 d0 = *(const float4*)(kb_ + (rkey0 + 1) * 32 + rc0);
        float4 d1 = *(const float4*)(kb_ + (rkey0 + 1) * 32 + rc1);
        union { bf16x8 v; unsigned u[4]; } kf0, kf1;
        kf0.u[0] = pk2(e0.x, e0.y); kf0.u[1] = pk2(e0.z, e0.w);
        kf0.u[2] = pk2(e1.x, e1.y); kf0.u[3] = pk2(e1.z, e1.w);
        kf1.u[0] = pk2(d0.x, d0.y); kf1.u[1] = pk2(d0.z, d0.w);
        kf1.u[2] = pk2(d1.x, d1.y); kf1.u[3] = pk2(d1.z, d1.w);

        // ---- S^T tiles: A=K (rows=keys), B=Q (cols=queries) ----
        f32x4 s00 = __builtin_amdgcn_mfma_f32_16x16x32_bf16(kf0.v, aQ0.v, zero, 0, 0, 0);
        f32x4 s01 = __builtin_amdgcn_mfma_f32_16x16x32_bf16(kf1.v, aQ0.v, zero, 0, 0, 0);
        f32x4 s10 = __builtin_amdgcn_mfma_f32_16x16x32_bf16(kf0.v, aQ1.v, zero, 0, 0, 0);
        f32x4 s11 = __builtin_amdgcn_mfma_f32_16x16x32_bf16(kf1.v, aQ1.v, zero, 0, 0, 0);

        // ---- V^T frags (bf16, b64 pairs) ----
        const unsigned short* vt = &Vst[buf][0];
        union { bf16x8 v; uint2 h[2]; } V0, V1;
        {
            const unsigned short* p0 = vt + l16 * PROW + quad * 8;
            V0.h[0] = *(const uint2*)p0;
            V0.h[1] = *(const uint2*)(p0 + 4);
            const unsigned short* p1 = vt + (16 + l16) * PROW + quad * 8;
            V1.h[0] = *(const uint2*)p1;
            V1.h[1] = *(const uint2*)(p1 + 4);
        }

        // ---- exp + pack straight into PV A-frags ----
        union { bf16x8 v; unsigned u[4]; } aP0, aP1;
        #pragma unroll
        for (int r = 0; r < 4; ++r) {
            float e0_  = __builtin_amdgcn_exp2f(s00[r]);
            float en0_ = __builtin_amdgcn_exp2f(-s00[r]);
            float e1_  = __builtin_amdgcn_exp2f(s01[r]);
            float en1_ = __builtin_amdgcn_exp2f(-s01[r]);
            den0 += (e0_ + en0_) + (e1_ + en1_);
            aP0.u[r] = pk2(e0_ - en0_, e1_ - en1_);
        }
        #pragma unroll
        for (int r = 0; r < 4; ++r) {
            float e0_  = __builtin_amdgcn_exp2f(s10[r]);
            float en0_ = __builtin_amdgcn_exp2f(-s10[r]);
            float e1_  = __builtin_amdgcn_exp2f(s11[r]);
            float en1_ = __builtin_amdgcn_exp2f(-s11[r]);
            den1 += (e0_ + en0_) + (e1_ + en1_);
            aP1.u[r] = pk2(e0_ - en0_, e1_ - en1_);
        }

        // ---- PV ----
        o00 = __builtin_amdgcn_mfma_f32_16x16x32_bf16(aP0.v, V0.v, o00, 0, 0, 0);
        o01 = __builtin_amdgcn_mfma_f32_16x16x32_bf16(aP0.v, V1.v, o01, 0, 0, 0);
        o10 = __builtin_amdgcn_mfma_f32_16x16x32_bf16(aP1.v, V0.v, o10, 0, 0, 0);
        o11 = __builtin_amdgcn_mfma_f32_16x16x32_bf16(aP1.v, V1.v, o11, 0, 0, 0);

        // ---- finish staging chunk c+1: convert + transpose-write V ----
        if (c + 1 < NCH) {
            unsigned short* vtw = &Vst[nbuf][0];
            vtw[(vcol + 0) * PROW + grow] = f2b(vreg.x);
            vtw[(vcol + 1) * PROW + grow] = f2b(vreg.y);
            vtw[(vcol + 2) * PROW + grow] = f2b(vreg.z);
            vtw[(vcol + 3) * PROW + grow] = f2b(vreg.w);
        }
        __syncthreads();
    }

    // ---- epilogue (per-wave; no cross-wave combine) ----
    den0 += __shfl_xor(den0, 16); den0 += __shfl_xor(den0, 32);
    den1 += __shfl_xor(den1, 16); den1 += __shfl_xor(den1, 32);

    float* outp = Out + ((size_t)bh * SLEN + qbase) * DK;
    #pragma unroll
    for (int rr = 0; rr < 4; ++rr) {
        float inv0 = 1.0f / __shfl(den0, quad * 4 + rr, 16);
        float inv1 = 1.0f / __shfl(den1, quad * 4 + rr, 16);
        int q0 = quad * 4 + rr;
        int q1 = 16 + quad * 4 + rr;
        outp[(size_t)q0 * DK + l16]      = o00[rr] * inv0;
        outp[(size_t)q0 * DK + 16 + l16] = o01[rr] * inv0;
        outp[(size_t)q1 * DK + l16]      = o10[rr] * inv1;
        outp[(size_t)q1 * DK + 16 + l16] = o11[rr] * inv1;
    }
}

extern "C" void kernel_launch(void* const* d_in, const int* in_sizes, int n_in,
                              void* d_out, int out_size, void* d_ws, size_t ws_size,
                              hipStream_t stream) {
    const float* Q = (const float*)d_in[0];
    const float* K = (const float*)d_in[1];
    const float* V = (const float*)d_in[2];
    // d_in[3] = attn_mask: no-op in reference, never read. d_ws: unused.
    float* Out = (float*)d_out;
    attn_fused<<<dim3(NBH * 16), dim3(256), 0, stream>>>(Q, K, V, Out);
}